// Round 2
// baseline (224.155 us; speedup 1.0000x reference)
//
#include <hip/hip_runtime.h>

constexpr int NN = 100000;   // nodes
constexpr int NE = 1600000;  // edges
constexpr int F  = 64;       // F_IN == F_OUT

typedef short bf16x8 __attribute__((ext_vector_type(8)));
typedef float f32x4  __attribute__((ext_vector_type(4)));
typedef unsigned uint4e __attribute__((ext_vector_type(4)));  // clang-native, ok for nontemporal builtins

// bf16 helpers: bf16 bits<<16 == fp32 bit pattern.
__device__ __forceinline__ float bf_lo(unsigned u) { return __uint_as_float(u << 16); }
__device__ __forceinline__ float bf_hi(unsigned u) { return __uint_as_float(u & 0xFFFF0000u); }
__device__ __forceinline__ unsigned pack_bf16(float a, float b) {  // RNE
    unsigned ua = __float_as_uint(a);
    unsigned ub = __float_as_uint(b);
    ua = (ua + 0x7FFFu + ((ua >> 16) & 1u)) >> 16;
    ub = (ub + 0x7FFFu + ((ub >> 16) & 1u)) & 0xFFFF0000u;
    return ua | ub;
}

// ---------------------------------------------------------------------------
// K1 prep: ONE dispatch, partitioned by blockIdx:
//   blocks [0,3125):      x fp32 -> bf16, 8 elems/thread (3125*256*8 = NN*F)
//   blocks [3125,9375):   row_ptr via edge-boundary scatter (thread per edge;
//                         rows sorted, so only boundary edges write)
//   blocks [9375,9423):   W [192][64] fp32 -> Wt [64][192] bf16 (transposed)
// ---------------------------------------------------------------------------
constexpr int B_CVT = NN * F / 8 / 256;        // 3125
constexpr int B_RP  = NE / 256;                // 6250
constexpr int B_W   = 192 * 64 / 256;          // 48

__global__ __launch_bounds__(256)
void prep_k(const float* __restrict__ x, ushort* __restrict__ xb,
            const int* __restrict__ rows, int* __restrict__ row_ptr,
            const float* __restrict__ w, ushort* __restrict__ wt) {
    const int b = blockIdx.x;
    if (b < B_CVT) {
        int tid = b * 256 + threadIdx.x;
        const float4* p = (const float4*)x + (size_t)tid * 2;
        float4 a = p[0], c = p[1];
        uint4 o = make_uint4(pack_bf16(a.x, a.y), pack_bf16(a.z, a.w),
                             pack_bf16(c.x, c.y), pack_bf16(c.z, c.w));
        ((uint4*)xb)[tid] = o;
    } else if (b < B_CVT + B_RP) {
        int e = (b - B_CVT) * 256 + threadIdx.x;
        int r1 = rows[e];
        int r2 = (e == NE - 1) ? NN : rows[e + 1];
        for (int r = r1 + 1; r <= r2; ++r) row_ptr[r] = e + 1;
        if (e == 0)
            for (int r = 0; r <= r1; ++r) row_ptr[r] = 0;
    } else {
        int tid = (b - B_CVT - B_RP) * 256 + threadIdx.x;
        int k = tid >> 6, n = tid & 63;
        unsigned u = __float_as_uint(w[tid]);
        u = (u + 0x7FFFu + ((u >> 16) & 1u)) >> 16;
        wt[n * 192 + k] = (ushort)u;
    }
}

// ---------------------------------------------------------------------------
// K2/K3: reduction-free bf16 SpMM. 8 rows per wave: egrp = lane>>3 OWNS row
// rbase+egrp, fgrp = lane&7 covers features [8*fgrp, +8) via one 16B load.
// v2: 2-stage software pipeline, depth P=4. The old loop had a serial
// cols[e] -> gather chain with unroll-2 ILP (<=2 gathers in flight); random
// gathers miss L1 always and per-XCD L2 ~70% (src=12.8MB vs 4MB L2), so the
// wave sat in vmcnt waits. Now: edge (col,val) regs are prefetched one batch
// (P edges) ahead, and P gathers are issued back-to-back before any FMA
// consumes them -> 4 outstanding gathers/wave + decoupled edge loads.
// cols/vals/x0 streams use nontemporal hints so the 12.8MB edge stream does
// not evict gather-resident src lines from L2.
// Inactive rows clamp to their last edge (L1-resident re-read, vj=0).
// Store: full wave writes 8 consecutive rows = 1KB contiguous.
// SECOND: dst = 2*A@src - x0 (Chebyshev fused).
// ---------------------------------------------------------------------------
template<bool SECOND>
__global__ __launch_bounds__(256)
void spmm_k(const int* __restrict__ row_ptr, const int* __restrict__ cols,
            const float* __restrict__ vals, const ushort* __restrict__ src,
            const ushort* __restrict__ x0, ushort* __restrict__ dst) {
    const int lane = threadIdx.x & 63;
    const int fgrp = lane & 7;
    const int g    = lane >> 3;                       // row within group
    const int r    = (blockIdx.x * 4 + (threadIdx.x >> 6)) * 8 + g;  // < NN
    const int e0 = row_ptr[r];
    const int e1 = row_ptr[r + 1];
    const int deg = e1 - e0;
    int maxdeg = deg;                                  // wave-max over the 8 rows
    maxdeg = max(maxdeg, __shfl_xor(maxdeg, 8));
    maxdeg = max(maxdeg, __shfl_xor(maxdeg, 16));
    maxdeg = max(maxdeg, __shfl_xor(maxdeg, 32));

    const int elast = max(e1 - 1, 0);                  // valid clamp target

    constexpr int P = 4;                               // pipeline depth
    int   cq[P]; float vq[P];
    #pragma unroll
    for (int i = 0; i < P; ++i) {                      // prologue: edges 0..P-1
        const bool a = i < deg;
        const int ec = a ? (e0 + i) : elast;
        cq[i] = __builtin_nontemporal_load(cols + ec);
        const float vv = __builtin_nontemporal_load(vals + ec);
        vq[i] = a ? vv : 0.f;
    }

    float acc[8] = {};
    for (int s = 0; s < maxdeg; s += P) {
        // issue all P gathers first (addresses ready since last batch)
        uint4e raw[P];
        #pragma unroll
        for (int i = 0; i < P; ++i)
            raw[i] = *(const uint4e*)(src + (size_t)cq[i] * F + fgrp * 8);
        // prefetch next batch of edges while gathers are in flight
        int   cn[P]; float vn[P];
        #pragma unroll
        for (int i = 0; i < P; ++i) {
            const int ss = s + P + i;
            const bool a = ss < deg;
            const int ec = a ? (e0 + ss) : elast;
            cn[i] = __builtin_nontemporal_load(cols + ec);
            const float vv = __builtin_nontemporal_load(vals + ec);
            vn[i] = a ? vv : 0.f;
        }
        // consume gathers
        #pragma unroll
        for (int i = 0; i < P; ++i) {
            const float vj = vq[i];
            acc[0] += vj * bf_lo(raw[i].x); acc[1] += vj * bf_hi(raw[i].x);
            acc[2] += vj * bf_lo(raw[i].y); acc[3] += vj * bf_hi(raw[i].y);
            acc[4] += vj * bf_lo(raw[i].z); acc[5] += vj * bf_hi(raw[i].z);
            acc[6] += vj * bf_lo(raw[i].w); acc[7] += vj * bf_hi(raw[i].w);
        }
        // rotate pipeline regs (renamed away by the compiler)
        #pragma unroll
        for (int i = 0; i < P; ++i) { cq[i] = cn[i]; vq[i] = vn[i]; }
    }

    float o[8];
    if (SECOND) {
        const uint4e* xp = (const uint4e*)(x0 + (size_t)r * F + fgrp * 8);
        uint4e xr = __builtin_nontemporal_load(xp);
        o[0] = 2.f * acc[0] - bf_lo(xr.x); o[1] = 2.f * acc[1] - bf_hi(xr.x);
        o[2] = 2.f * acc[2] - bf_lo(xr.y); o[3] = 2.f * acc[3] - bf_hi(xr.y);
        o[4] = 2.f * acc[4] - bf_lo(xr.z); o[5] = 2.f * acc[5] - bf_hi(xr.z);
        o[6] = 2.f * acc[6] - bf_lo(xr.w); o[7] = 2.f * acc[7] - bf_hi(xr.w);
    } else {
        #pragma unroll
        for (int t = 0; t < 8; ++t) o[t] = acc[t];
    }
    uint4 ov = make_uint4(pack_bf16(o[0], o[1]), pack_bf16(o[2], o[3]),
                          pack_bf16(o[4], o[5]), pack_bf16(o[6], o[7]));
    *(uint4*)(dst + (size_t)r * F + fgrp * 8) = ov;
}

// ---------------------------------------------------------------------------
// K4: dense epilogue via bf16 MFMA, LDS-transposed coalesced stores.
// out[100000x64] = [x|t1|t2](bf16, Nx192) @ Wt^T + bias, fp32 out.
// Wave w: rows [blk*64 + 16w, +16), all 64 cols. A-frag/B-frag = one 16B
// load each (A[m=lane&15][k=quad*8+j]; Wt[n][k] row-contig). C/D layout:
// col=lane&15, row=quad*4+reg. Epilogue: scatter acc(+bias) into a per-wave
// LDS slab (stride 68 floats: 16B-aligned rows, <=2-way banks = free), then
// 4 full-row float4 coalesced stores.
// ---------------------------------------------------------------------------
__global__ __launch_bounds__(256)
void dense_k(const ushort* __restrict__ xb, const ushort* __restrict__ t1,
             const ushort* __restrict__ t2, const ushort* __restrict__ wt,
             const float* __restrict__ bias, float* __restrict__ out) {
    __shared__ float lds[4][16 * 68];
    const int tid  = threadIdx.x;
    const int lane = tid & 63;
    const int wv   = tid >> 6;
    const int row0 = blockIdx.x * 64 + wv * 16;
    const int m    = lane & 15;
    const int quad = lane >> 4;
    int arow = row0 + m;
    if (arow >= NN) arow = NN - 1;          // clamp; stores are guarded

    f32x4 acc[4] = {};
    #pragma unroll
    for (int kb = 0; kb < 6; ++kb) {
        const int kbase = kb * 32;
        const ushort* seg = (kb < 2) ? xb : (kb < 4) ? t1 : t2;
        const int off = (kbase & 63) + quad * 8;
        bf16x8 a = *(const bf16x8*)(seg + (size_t)arow * F + off);
        #pragma unroll
        for (int t = 0; t < 4; ++t) {
            const int n = t * 16 + m;
            bf16x8 b = *(const bf16x8*)(wt + (size_t)n * 192 + kbase + quad * 8);
            acc[t] = __builtin_amdgcn_mfma_f32_16x16x32_bf16(a, b, acc[t], 0, 0, 0);
        }
    }

    float* sl = lds[wv];
    #pragma unroll
    for (int t = 0; t < 4; ++t) {
        const float bv = bias[t * 16 + m];
        #pragma unroll
        for (int rr = 0; rr < 4; ++rr)
            sl[(quad * 4 + rr) * 68 + t * 16 + m] = acc[t][rr] + bv;
    }
    __syncthreads();
    // read back row-major, store coalesced: pass p covers 4 rows x 256B
    const int m4 = (lane & 15) * 4;
    #pragma unroll
    for (int p = 0; p < 4; ++p) {
        const int rl = p * 4 + (lane >> 4);
        const int grow = row0 + rl;
        f32x4 v = *(const f32x4*)(sl + rl * 68 + m4);
        if (grow < NN)
            *(f32x4*)(out + (size_t)grow * F + m4) = v;
    }
}

extern "C" void kernel_launch(void* const* d_in, const int* in_sizes, int n_in,
                              void* d_out, int out_size, void* d_ws, size_t ws_size,
                              hipStream_t stream) {
    const float* x    = (const float*)d_in[0];
    const int*   rows = (const int*)  d_in[1];
    const int*   cols = (const int*)  d_in[2];
    const float* vals = (const float*)d_in[3];
    const float* w    = (const float*)d_in[4];  // [3][64][64] == [192][64]
    const float* bias = (const float*)d_in[5];  // [64]
    float* out = (float*)d_out;

    // Workspace (all fully rewritten every call; safe vs 0xAA poison):
    //   row_ptr (NN+1 int) | xb, t1b, t2b (N*64 bf16 each, 12.8MB) | wt (24KB)
    char* ws = (char*)d_ws;
    int* row_ptr = (int*)ws;
    size_t off = (((size_t)(NN + 1) * sizeof(int)) + 255) & ~(size_t)255;
    ushort* xb  = (ushort*)(ws + off);
    ushort* t1b = xb  + (size_t)NN * F;
    ushort* t2b = t1b + (size_t)NN * F;
    ushort* wt  = t2b + (size_t)NN * F;

    prep_k<<<B_CVT + B_RP + B_W, 256, 0, stream>>>(x, xb, rows, row_ptr, w, wt);
    spmm_k<false><<<NN / 32, 256, 0, stream>>>(row_ptr, cols, vals, xb,  nullptr, t1b);
    spmm_k<true ><<<NN / 32, 256, 0, stream>>>(row_ptr, cols, vals, t1b, xb,      t2b);
    dense_k<<<(NN + 63) / 64, 256, 0, stream>>>(xb, t1b, t2b, wt, bias, out);
}